// Round 16
// baseline (71.837 us; speedup 1.0000x reference)
//
#include <hip/hip_runtime.h>

typedef __attribute__((ext_vector_type(8))) __bf16 bf16x8;
typedef __attribute__((ext_vector_type(4))) float f32x4;

#define M_ 256
#define N_ 4096
#define K_ 4096
#define BM 64
#define BN 64
#define NSTEP 128          // K_/32 k-steps
#define QSTEP 32           // steps per quarter (1024 k)

// Tiled operand layout: 1KB bf16 tile = 16 rows x 32 k; tile(rt,kt) index
// rt*128+kt; slot lane = (row&15)+16*((k>>3)&3), elem = k&7.
// Because frag-slot == lane, every MFMA fragment is ONE coalesced 16B/lane
// global load — the GEMM runs entirely from registers (no LDS, no barriers).
// xgh/xgl: 16B/slot bf16. z2: 2B/slot = 8x2-bit lattice indices.

// ---------- helpers ----------

__device__ __forceinline__ unsigned short f2bf(float f) {
  unsigned int u = __builtin_bit_cast(unsigned int, f);
  u += 0x7fffu + ((u >> 16) & 1u);
  return (unsigned short)(u >> 16);
}

__device__ __forceinline__ float lsq1(float y, float a, float s) {
  float yc = fminf(fmaxf(y, -a), a);
  return rintf(yc / s) * s;
}

// decode 8x2-bit word -> 8 bf16 (values idx-2 in {-2,-1,0,1}), ascending elems.
// v_cvt_pk_bf16_f32 on exact small ints == ZLUT bits (verified R14/R15).
__device__ __forceinline__ bf16x8 zdec_pk(unsigned int w) {
  unsigned int d0, d1, d2, d3;
#define ZP(P, D)                                                        \
  {                                                                     \
    const float f0 = (float)((w >> (4 * P)) & 3u) - 2.0f;               \
    const float f1 = (float)((w >> (4 * P + 2)) & 3u) - 2.0f;           \
    asm("v_cvt_pk_bf16_f32 %0, %1, %2" : "=v"(D) : "v"(f0), "v"(f1));   \
  }
  ZP(0, d0) ZP(1, d1) ZP(2, d2) ZP(3, d3)
#undef ZP
  const uint4 u = make_uint4(d0, d1, d2, d3);
  return __builtin_bit_cast(bf16x8, u);
}

// ---------- K1: fused producer (verified R13 — DO NOT TOUCH) ----------
// blocks [0, NQB): lattice-quantize W -> z2 (2-bit indices, tiled slot order).
//   z dot: f32 UNFUSED mul+add, sequential ascending, contract(off) — matches
//   XLA:CPU's fmul/fadd chain (contraction was the R1/R9/R10 0.701 bug; R10's
//   "bisection" was confounded because BOTH halves contained this broken prep).
// blocks [NQB, NQB+NXB): xg = x_blocks @ G^T -> bf16 hi/lo (tiled layout).

#define NQB ((N_ * K_ / 8) / 256)  // 8192
#define NXB ((M_ * K_ / 8) / 256)  // 512

__global__ __launch_bounds__(256) void k_prep(const float* __restrict__ W,
                                              const float* __restrict__ theta,
                                              const float* __restrict__ Ginv,
                                              const float* __restrict__ x,
                                              const float* __restrict__ G,
                                              unsigned short* __restrict__ z2,
                                              unsigned short* __restrict__ hi,
                                              unsigned short* __restrict__ lo,
                                              int kTheta) {
  __shared__ float Ms[64];
  const int tid = threadIdx.x;
  const bool isQ = blockIdx.x < NQB;
  if (tid < 64) Ms[tid] = isQ ? Ginv[tid] : G[tid];
  __syncthreads();

  if (isQ) {
#pragma clang fp contract(off)
    const int s = blockIdx.x * 256 + tid;       // output slot
    const int lane6 = s & 63;
    const int tile = s >> 6;
    const int o  = ((tile >> 7) << 4) + (lane6 & 15);   // W row
    const int kb = ((tile & 127) << 2) + (lane6 >> 4);  // 8-elt k-block
    const float4* wp = (const float4*)(W + ((size_t)o << 12) + ((size_t)kb << 3));
    const float4 w0 = wp[0], w1 = wp[1];
    float sc = 0.f;
    for (int t = 0; t < kTheta; ++t) sc += theta[o * kTheta + t];
    sc /= (float)kTheta;
    const float wsv[8] = {w0.x * sc, w0.y * sc, w0.z * sc, w0.w * sc,
                          w1.x * sc, w1.y * sc, w1.z * sc, w1.w * sc};
    unsigned int word = 0u;
#pragma unroll
    for (int i = 0; i < 8; ++i) {
      float t = 0.f;
#pragma unroll
      for (int j = 0; j < 8; ++j)
        t = t + wsv[j] * Ms[j * 8 + i];   // contract(off): separate rn mul + rn add
      const int zi = (int)rintf(t);
      word |= (unsigned int)((zi + 2) & 3) << (2 * i);
    }
    z2[s] = (unsigned short)word;
  } else {
    const int s = (blockIdx.x - NQB) * 256 + tid;
    const int lane6 = s & 63;
    const int tile = s >> 6;
    const int m  = ((tile >> 7) << 4) + (lane6 & 15);
    const int kb = ((tile & 127) << 2) + (lane6 >> 4);
    const float4* xp = (const float4*)(x + ((size_t)m << 12) + ((size_t)kb << 3));
    const float4 a0 = xp[0], a1 = xp[1];
    float xv[8] = {a0.x, a0.y, a0.z, a0.w, a1.x, a1.y, a1.z, a1.w};
    unsigned int ph[4] = {0u, 0u, 0u, 0u}, pl[4] = {0u, 0u, 0u, 0u};
#pragma unroll
    for (int i = 0; i < 8; ++i) {
      float t = 0.f;
#pragma unroll
      for (int j = 0; j < 8; ++j) t = fmaf(xv[j], Ms[i * 8 + j], t);
      const unsigned short hb = f2bf(t);
      const float hf = __builtin_bit_cast(float, (unsigned int)hb << 16);
      const unsigned short lb = f2bf(t - hf);
      ph[i >> 1] |= ((unsigned int)hb) << ((i & 1) * 16);
      pl[i >> 1] |= ((unsigned int)lb) << ((i & 1) * 16);
    }
    *(uint4*)(hi + ((size_t)s << 3)) = make_uint4(ph[0], ph[1], ph[2], ph[3]);
    *(uint4*)(lo + ((size_t)s << 3)) = make_uint4(pl[0], pl[1], pl[2], pl[3]);
  }
}

// ---------- K2: all-register FULL-K GEMM + fused bias/LSQ epilogue ----------
// grid 256 = (mt 4) x (nt 64); 512 thr = 8 waves (4m x 2n), wave out 16x32.
// Full K in 128 steps of 32; FOUR quarter-accumulators acc[q][nf] (q = k/1024,
// outer q-loop unrolled -> static indexing) reduced in the epilogue in EXACTLY
// the verified k_epi order ((q0+q1)+q2)+q3 + bias -> output bit-identical to
// R13/R15. Per step: 2 A loads (bf16x8, L2-resident) + 1 z2 word -> zdec_pk
// + 2 MFMA/nf. 2-deep register prefetch; no LDS, no barriers, no partials.
// b&3 = mt -> per-XCD 1MB A-slice stays L2-resident across its 32 nt-blocks.
// Per-accumulator MFMA k-order (ascending k32, hi-then-lo) = verified r3-r15.

__global__ __launch_bounds__(512, 2) void k_gemm(const unsigned short* __restrict__ xgh,
                                                 const unsigned short* __restrict__ xgl,
                                                 const unsigned short* __restrict__ z2,
                                                 const float* __restrict__ bias,
                                                 const float* __restrict__ alpha,
                                                 float* __restrict__ out) {
  const int tid = threadIdx.x;
  const int lane = tid & 63, wave = tid >> 6;
  const int wr = wave >> 1, wc = wave & 1;   // wave grid 4m x 2n
  const int b = blockIdx.x;
  const int mt = b & 3;                      // 0..3  (b&7 spans mt x nt-parity per XCD)
  const int nt = b >> 2;                     // 0..63
  const int lrow = lane & 15, lkg = lane >> 4;

  // A: wave's 16 rows = row-tile rt = mt*4 + wr
  const size_t ta = (size_t)((mt * 4 + wr) * 128) << 9;
  const unsigned short* ah_p = xgh + ta + lane * 8;
  const unsigned short* al_p = xgl + ta + lane * 8;
  // B: n-frag nf -> row-tile nt*4 + wc*2 + nf
  const unsigned short* zb[2];
#pragma unroll
  for (int nf = 0; nf < 2; ++nf)
    zb[nf] = z2 + (((size_t)((nt * 4 + wc * 2 + nf) * 128)) << 6) + lane;

  f32x4 acc[4][2] = {};   // [k-quarter][nf]

  // prologue: load step 0
  bf16x8 cah = *(const bf16x8*)(ah_p);
  bf16x8 cal = *(const bf16x8*)(al_p);
  unsigned int czw[2] = {zb[0][0], zb[1][0]};

#pragma unroll
  for (int q = 0; q < 4; ++q) {
    for (int t = 0; t < QSTEP; ++t) {
      const int ks = q * QSTEP + t;
      bf16x8 nah, nal;
      unsigned int nzw[2];
      if (ks + 1 < NSTEP) {
        nah = *(const bf16x8*)(ah_p + (size_t)(ks + 1) * 512);
        nal = *(const bf16x8*)(al_p + (size_t)(ks + 1) * 512);
        nzw[0] = zb[0][(size_t)(ks + 1) * 64];
        nzw[1] = zb[1][(size_t)(ks + 1) * 64];
      } else {
        nah = cah; nal = cal; nzw[0] = czw[0]; nzw[1] = czw[1];
      }

      bf16x8 bfr[2];
#pragma unroll
      for (int nf = 0; nf < 2; ++nf) bfr[nf] = zdec_pk(czw[nf]);

#pragma unroll
      for (int nf = 0; nf < 2; ++nf) {
        acc[q][nf] = __builtin_amdgcn_mfma_f32_16x16x32_bf16(cah, bfr[nf], acc[q][nf], 0, 0, 0);
        acc[q][nf] = __builtin_amdgcn_mfma_f32_16x16x32_bf16(cal, bfr[nf], acc[q][nf], 0, 0, 0);
      }

      cah = nah; cal = nal; czw[0] = nzw[0]; czw[1] = nzw[1];
    }
  }

  // fused epilogue: quarter-reduce in k_epi's exact order + bias + LSQ.
  // C/D layout (m89-verified): col = lane&15, row = (lane>>4)*4 + reg
  const float a = fmaxf(alpha[0], 0.f) + 1e-8f;
  const float s = a / 127.0f;
#pragma unroll
  for (int nf = 0; nf < 2; ++nf) {
    const int n = nt * BN + wc * 32 + nf * 16 + lrow;
    const float bv = bias[n];
#pragma unroll
    for (int r = 0; r < 4; ++r) {
      const int m = mt * BM + wr * 16 + lkg * 4 + r;
      const float y = ((acc[0][nf][r] + acc[1][nf][r]) + acc[2][nf][r]) + acc[3][nf][r] + bv;
      out[(size_t)m * N_ + n] = lsq1(y, a, s);
    }
  }
}

// ---------- launch ----------

extern "C" void kernel_launch(void* const* d_in, const int* in_sizes, int n_in,
                              void* d_out, int out_size, void* d_ws, size_t ws_size,
                              hipStream_t stream) {
  const float* x     = (const float*)d_in[0];
  const float* W     = (const float*)d_in[1];
  const float* bias  = (const float*)d_in[2];
  const float* theta = (const float*)d_in[3];
  const float* alpha = (const float*)d_in[4];
  const float* G     = (const float*)d_in[5];
  const float* Ginv  = (const float*)d_in[6];
  float* out = (float*)d_out;

  const int O = in_sizes[2];           // 4096
  const int kTheta = in_sizes[3] / O;  // 1

  // ws layout: xg_hi 2MB | xg_lo 2MB | z2 4MB
  char* ws = (char*)d_ws;
  unsigned short* xgh = (unsigned short*)ws;
  unsigned short* xgl = (unsigned short*)(ws + 2097152);
  unsigned short* z2  = (unsigned short*)(ws + 4194304);
  if (ws_size < 8388608) return;  // guard: need 8MB scratch

  k_prep<<<NQB + NXB, 256, 0, stream>>>(W, theta, Ginv, x, G, z2, xgh, xgl, kTheta);
  k_gemm<<<4 * (N_ / BN), 512, 0, stream>>>(xgh, xgl, z2, bias, alpha, out);
}

// Round 17
// 58.655 us; speedup vs baseline: 1.2247x; 1.2247x over previous
//
#include <hip/hip_runtime.h>

typedef __attribute__((ext_vector_type(8))) __bf16 bf16x8;
typedef __attribute__((ext_vector_type(4))) float f32x4;

#define M_ 256
#define N_ 4096
#define K_ 4096
#define SPLITK 4
#define KC (K_ / SPLITK)   // 1024
#define BM 128
#define BN 64
#define BK 32
#define KSTEPS (KC / BK)   // 32

// Tiled operand layout: 1KB bf16 tile = 16 rows x 32 k; tile(rt,kt) index
// rt*128+kt; slot lane = (row&15)+16*((k>>3)&3), elem = k&7.
// Because frag-slot == lane, every MFMA fragment is ONE coalesced 16B/lane
// global load — the GEMM runs entirely from registers: no LDS, no barriers,
// and (R16 lesson: decode was VALU-bound) NO in-GEMM decode — zq stores the
// lattice values as ready-to-MFMA bf16.

// ---------- helpers ----------

__device__ __forceinline__ unsigned short f2bf(float f) {
  unsigned int u = __builtin_bit_cast(unsigned int, f);
  u += 0x7fffu + ((u >> 16) & 1u);
  return (unsigned short)(u >> 16);
}

__device__ __forceinline__ float lsq1(float y, float a, float s) {
  float yc = fminf(fmaxf(y, -a), a);
  return rintf(yc / s) * s;
}

// ---------- K1: fused producer ----------
// blocks [0, NQB): lattice-quantize W -> zq (bf16 bits via LUT, tiled slots).
//   z dot: f32 UNFUSED mul+add, sequential ascending, contract(off) — matches
//   XLA:CPU's fmul/fadd chain (contraction was the R1/R9/R10 0.701 bug; the
//   zq-LUT variant passed R3-R8/R11/R12 and contract(off) pins that codegen).
// blocks [NQB, NQB+NXB): xg = x_blocks @ G^T -> bf16 hi/lo (tiled layout).

#define NQB ((N_ * K_ / 8) / 256)  // 8192
#define NXB ((M_ * K_ / 8) / 256)  // 512

__global__ __launch_bounds__(256) void k_prep(const float* __restrict__ W,
                                              const float* __restrict__ theta,
                                              const float* __restrict__ Ginv,
                                              const float* __restrict__ x,
                                              const float* __restrict__ G,
                                              unsigned short* __restrict__ zq,
                                              unsigned short* __restrict__ hi,
                                              unsigned short* __restrict__ lo,
                                              int kTheta) {
  __shared__ float Ms[64];
  const int tid = threadIdx.x;
  const bool isQ = blockIdx.x < NQB;
  if (tid < 64) Ms[tid] = isQ ? Ginv[tid] : G[tid];
  __syncthreads();

  if (isQ) {
#pragma clang fp contract(off)
    const int s = blockIdx.x * 256 + tid;       // output 16B slot
    const int lane6 = s & 63;
    const int tile = s >> 6;
    const int o  = ((tile >> 7) << 4) + (lane6 & 15);   // W row
    const int kb = ((tile & 127) << 2) + (lane6 >> 4);  // 8-elt k-block
    const float4* wp = (const float4*)(W + ((size_t)o << 12) + ((size_t)kb << 3));
    const float4 w0 = wp[0], w1 = wp[1];
    float sc = 0.f;
    for (int t = 0; t < kTheta; ++t) sc += theta[o * kTheta + t];
    sc /= (float)kTheta;
    const float wsv[8] = {w0.x * sc, w0.y * sc, w0.z * sc, w0.w * sc,
                          w1.x * sc, w1.y * sc, w1.z * sc, w1.w * sc};
    unsigned int packed[4] = {0u, 0u, 0u, 0u};
    const unsigned long long lut = 0x3F800000BF80C000ull;  // idx 0..3 -> -2,-1,0,+1 (bf16)
#pragma unroll
    for (int i = 0; i < 8; ++i) {
      float t = 0.f;
#pragma unroll
      for (int j = 0; j < 8; ++j)
        t = t + wsv[j] * Ms[j * 8 + i];   // contract(off): separate rn mul + rn add
      const int zi = (int)rintf(t);
      const int idx = (zi + 2) & 3;
      const unsigned int h = (unsigned int)((lut >> (idx * 16)) & 0xFFFFull);
      packed[i >> 1] |= h << ((i & 1) * 16);
    }
    *(uint4*)(zq + ((size_t)s << 3)) = make_uint4(packed[0], packed[1], packed[2], packed[3]);
  } else {
    const int s = (blockIdx.x - NQB) * 256 + tid;
    const int lane6 = s & 63;
    const int tile = s >> 6;
    const int m  = ((tile >> 7) << 4) + (lane6 & 15);
    const int kb = ((tile & 127) << 2) + (lane6 >> 4);
    const float4* xp = (const float4*)(x + ((size_t)m << 12) + ((size_t)kb << 3));
    const float4 a0 = xp[0], a1 = xp[1];
    float xv[8] = {a0.x, a0.y, a0.z, a0.w, a1.x, a1.y, a1.z, a1.w};
    unsigned int ph[4] = {0u, 0u, 0u, 0u}, pl[4] = {0u, 0u, 0u, 0u};
#pragma unroll
    for (int i = 0; i < 8; ++i) {
      float t = 0.f;
#pragma unroll
      for (int j = 0; j < 8; ++j) t = fmaf(xv[j], Ms[i * 8 + j], t);
      const unsigned short hb = f2bf(t);
      const float hf = __builtin_bit_cast(float, (unsigned int)hb << 16);
      const unsigned short lb = f2bf(t - hf);
      ph[i >> 1] |= ((unsigned int)hb) << ((i & 1) * 16);
      pl[i >> 1] |= ((unsigned int)lb) << ((i & 1) * 16);
    }
    *(uint4*)(hi + ((size_t)s << 3)) = make_uint4(ph[0], ph[1], ph[2], ph[3]);
    *(uint4*)(lo + ((size_t)s << 3)) = make_uint4(pl[0], pl[1], pl[2], pl[3]);
  }
}

// ---------- K2: all-register split-K GEMM (no LDS, no barriers, NO DECODE) ----------
// 512 thr = 8 waves (4m x 2n), wave = 32x32 out, tile 128x64, BK=32.
// Grid 512 = 2 blocks/CU. Per step: 4 A loads + 2 B loads (all direct bf16x8,
// L2-resident), 8 MFMA. 2-deep register prefetch, compiler waitcnts.
// b&7 = (mt,sk) -> per-XCD L2 slice. Per-accumulator MFMA k-order
// (ascending k32, hi-then-lo) = verified r3-r16.

__global__ __launch_bounds__(512, 2) void k_gemm(const unsigned short* __restrict__ xgh,
                                                 const unsigned short* __restrict__ xgl,
                                                 const unsigned short* __restrict__ zq,
                                                 float* __restrict__ part) {
  const int tid = threadIdx.x;
  const int lane = tid & 63, wave = tid >> 6;
  const int wr = wave >> 1, wc = wave & 1;   // wave grid 4m x 2n
  const int b = blockIdx.x;
  const int mt = b & 1;
  const int sk = (b >> 1) & 3;
  const int nt = b >> 3;                     // 0..63
  const int k0t = sk * (KC / 32);            // base k-tile index
  const int lrow = lane & 15, lkg = lane >> 4;

  const unsigned short* ab[2];
  const unsigned short* lb2[2];
#pragma unroll
  for (int mf = 0; mf < 2; ++mf) {
    const size_t t = (size_t)((mt * 8 + wr * 2 + mf) * 128 + k0t);
    ab[mf]  = xgh + (t << 9) + lane * 8;
    lb2[mf] = xgl + (t << 9) + lane * 8;
  }
  const unsigned short* zb[2];
#pragma unroll
  for (int nf = 0; nf < 2; ++nf)
    zb[nf] = zq + (((size_t)((nt * 4 + wc * 2 + nf) * 128 + k0t)) << 9) + lane * 8;

  f32x4 acc[2][2] = {};

  // prologue: load step 0 into current set
  bf16x8 cah[2], cal[2], cbf[2];
#pragma unroll
  for (int mf = 0; mf < 2; ++mf) {
    cah[mf] = *(const bf16x8*)(ab[mf]);
    cal[mf] = *(const bf16x8*)(lb2[mf]);
  }
#pragma unroll
  for (int nf = 0; nf < 2; ++nf) cbf[nf] = *(const bf16x8*)(zb[nf]);

  for (int ks = 0; ks < KSTEPS; ++ks) {
    bf16x8 nah[2], nal[2], nbf[2];
    if (ks + 1 < KSTEPS) {
#pragma unroll
      for (int mf = 0; mf < 2; ++mf) {
        nah[mf] = *(const bf16x8*)(ab[mf] + (size_t)(ks + 1) * 512);
        nal[mf] = *(const bf16x8*)(lb2[mf] + (size_t)(ks + 1) * 512);
      }
#pragma unroll
      for (int nf = 0; nf < 2; ++nf)
        nbf[nf] = *(const bf16x8*)(zb[nf] + (size_t)(ks + 1) * 512);
    } else {
#pragma unroll
      for (int mf = 0; mf < 2; ++mf) { nah[mf] = cah[mf]; nal[mf] = cal[mf]; }
#pragma unroll
      for (int nf = 0; nf < 2; ++nf) nbf[nf] = cbf[nf];
    }

#pragma unroll
    for (int mf = 0; mf < 2; ++mf)
#pragma unroll
      for (int nf = 0; nf < 2; ++nf) {
        acc[mf][nf] = __builtin_amdgcn_mfma_f32_16x16x32_bf16(cah[mf], cbf[nf], acc[mf][nf], 0, 0, 0);
        acc[mf][nf] = __builtin_amdgcn_mfma_f32_16x16x32_bf16(cal[mf], cbf[nf], acc[mf][nf], 0, 0, 0);
      }

#pragma unroll
    for (int mf = 0; mf < 2; ++mf) { cah[mf] = nah[mf]; cal[mf] = nal[mf]; }
#pragma unroll
    for (int nf = 0; nf < 2; ++nf) cbf[nf] = nbf[nf];
  }

  // C/D layout (m89-verified): col = lane&15, row = (lane>>4)*4 + reg
  float* pb = part + (size_t)sk * (M_ * N_);
#pragma unroll
  for (int mf = 0; mf < 2; ++mf)
#pragma unroll
    for (int nf = 0; nf < 2; ++nf)
#pragma unroll
      for (int r = 0; r < 4; ++r) {
        const int m = mt * BM + wr * 32 + mf * 16 + lkg * 4 + r;
        const int n = nt * BN + wc * 32 + nf * 16 + lrow;
        pb[(size_t)m * N_ + n] = acc[mf][nf][r];
      }
}

// ---------- K3: reduce 4 split-K partials + bias + LSQ epilogue (verified) ----------

__global__ __launch_bounds__(256) void k_epi(const float* __restrict__ part,
                                             const float* __restrict__ bias,
                                             const float* __restrict__ alpha,
                                             float* __restrict__ out) {
  const int i4 = blockIdx.x * 256 + threadIdx.x;  // over M_*N_/4
  const size_t off = (size_t)i4 * 4;
  const float4 p0 = *(const float4*)(part + off);
  const float4 p1 = *(const float4*)(part + (size_t)1 * M_ * N_ + off);
  const float4 p2 = *(const float4*)(part + (size_t)2 * M_ * N_ + off);
  const float4 p3 = *(const float4*)(part + (size_t)3 * M_ * N_ + off);
  const int n = (int)(off & (N_ - 1));
  const float4 bv = *(const float4*)(bias + n);
  const float a = fmaxf(alpha[0], 0.f) + 1e-8f;
  const float s = a / 127.0f;
  float4 o;
  o.x = lsq1(((p0.x + p1.x) + p2.x) + p3.x + bv.x, a, s);
  o.y = lsq1(((p0.y + p1.y) + p2.y) + p3.y + bv.y, a, s);
  o.z = lsq1(((p0.z + p1.z) + p2.z) + p3.z + bv.z, a, s);
  o.w = lsq1(((p0.w + p1.w) + p2.w) + p3.w + bv.w, a, s);
  *(float4*)(out + off) = o;
}

// ---------- launch ----------

extern "C" void kernel_launch(void* const* d_in, const int* in_sizes, int n_in,
                              void* d_out, int out_size, void* d_ws, size_t ws_size,
                              hipStream_t stream) {
  const float* x     = (const float*)d_in[0];
  const float* W     = (const float*)d_in[1];
  const float* bias  = (const float*)d_in[2];
  const float* theta = (const float*)d_in[3];
  const float* alpha = (const float*)d_in[4];
  const float* G     = (const float*)d_in[5];
  const float* Ginv  = (const float*)d_in[6];
  float* out = (float*)d_out;

  const int O = in_sizes[2];           // 4096
  const int kTheta = in_sizes[3] / O;  // 1

  // ws layout: zq bf16 tiled 32MB | xg_hi 2MB | xg_lo 2MB | partials [4][M][N] 16MB
  char* ws = (char*)d_ws;
  unsigned short* zq  = (unsigned short*)ws;
  unsigned short* xgh = (unsigned short*)(ws + 33554432);
  unsigned short* xgl = (unsigned short*)(ws + 35651584);
  float* part = (float*)(ws + 37748736);
  if (ws_size < 54525952) return;  // guard: need 52MB scratch

  k_prep<<<NQB + NXB, 256, 0, stream>>>(W, theta, Ginv, x, G, zq, xgh, xgl, kTheta);
  k_gemm<<<2 * SPLITK * 64, 512, 0, stream>>>(xgh, xgl, zq, part);
  k_epi<<<(M_ * N_ / 4) / 256, 256, 0, stream>>>(part, bias, alpha, out);
}

// Round 18
// 52.462 us; speedup vs baseline: 1.3693x; 1.1181x over previous
//
#include <hip/hip_runtime.h>

typedef __attribute__((ext_vector_type(8))) __bf16 bf16x8;
typedef __attribute__((ext_vector_type(4))) float f32x4;

#define M_ 256
#define N_ 4096
#define K_ 4096
#define SPLITK 4
#define KC (K_ / SPLITK)   // 1024
#define BM 256             // all of M per block (tall block)
#define BN 64
#define BK 32
#define KSTEPS (KC / BK)   // 32
#define NCH 36             // 1KB chunks per K-step: A_hi 16 | A_lo 16 | B 4
#define LDSBUF 36864       // bytes per buffer

// Tiled operand layout: 1KB bf16 tile = 16 rows x 32 k; tile(rt,kt) index
// rt*128+kt; slot lane = (row&15)+16*((k>>3)&3), elem = k&7.
// xgh/xgl: 16B/slot bf16 (async16-staged). z2: 2B/slot = 8x2-bit indices,
// decoded in-GEMM (LUT) to the same bf16 bits — verified R13.

// ---------- helpers ----------

__device__ __forceinline__ unsigned short f2bf(float f) {
  unsigned int u = __builtin_bit_cast(unsigned int, f);
  u += 0x7fffu + ((u >> 16) & 1u);
  return (unsigned short)(u >> 16);
}

__device__ __forceinline__ void async16(const void* g, void* l) {
  __builtin_amdgcn_global_load_lds(
      (const __attribute__((address_space(1))) unsigned int*)g,
      (__attribute__((address_space(3))) unsigned int*)l, 16, 0, 0);
}

__device__ __forceinline__ float lsq1(float y, float a, float s) {
  float yc = fminf(fmaxf(y, -a), a);
  return rintf(yc / s) * s;
}

// bf16 bit patterns for z_mod = idx-2: idx 0->-2, 1->-1, 2->0, 3->+1
#define ZLUT 0x3F800000BF80C000ull

// decode 8x2-bit word -> 16B (8 bf16), elem order ascending (verified R13)
__device__ __forceinline__ uint4 zdec(unsigned int w) {
  unsigned int d[4];
#pragma unroll
  for (int p = 0; p < 4; ++p) {
    const unsigned int lo = (unsigned int)((ZLUT >> (((w >> (4 * p)) & 3u) * 16)) & 0xFFFFull);
    const unsigned int hi = (unsigned int)((ZLUT >> (((w >> (4 * p + 2)) & 3u) * 16)) & 0xFFFFull);
    d[p] = lo | (hi << 16);
  }
  return make_uint4(d[0], d[1], d[2], d[3]);
}

// ---------- K1: fused producer (verified R13 — DO NOT TOUCH) ----------
// blocks [0, NQB): lattice-quantize W -> z2 (2-bit indices, tiled slot order).
//   z dot: f32 UNFUSED mul+add, sequential ascending, contract(off) — matches
//   XLA:CPU's fmul/fadd chain (contraction was the R1/R9/R10 0.701 bug).
// blocks [NQB, NQB+NXB): xg = x_blocks @ G^T -> bf16 hi/lo (tiled layout).

#define NQB ((N_ * K_ / 8) / 256)  // 8192
#define NXB ((M_ * K_ / 8) / 256)  // 512

__global__ __launch_bounds__(256) void k_prep(const float* __restrict__ W,
                                              const float* __restrict__ theta,
                                              const float* __restrict__ Ginv,
                                              const float* __restrict__ x,
                                              const float* __restrict__ G,
                                              unsigned short* __restrict__ z2,
                                              unsigned short* __restrict__ hi,
                                              unsigned short* __restrict__ lo,
                                              int kTheta) {
  __shared__ float Ms[64];
  const int tid = threadIdx.x;
  const bool isQ = blockIdx.x < NQB;
  if (tid < 64) Ms[tid] = isQ ? Ginv[tid] : G[tid];
  __syncthreads();

  if (isQ) {
#pragma clang fp contract(off)
    const int s = blockIdx.x * 256 + tid;       // output slot
    const int lane6 = s & 63;
    const int tile = s >> 6;
    const int o  = ((tile >> 7) << 4) + (lane6 & 15);   // W row
    const int kb = ((tile & 127) << 2) + (lane6 >> 4);  // 8-elt k-block
    const float4* wp = (const float4*)(W + ((size_t)o << 12) + ((size_t)kb << 3));
    const float4 w0 = wp[0], w1 = wp[1];
    float sc = 0.f;
    for (int t = 0; t < kTheta; ++t) sc += theta[o * kTheta + t];
    sc /= (float)kTheta;
    const float wsv[8] = {w0.x * sc, w0.y * sc, w0.z * sc, w0.w * sc,
                          w1.x * sc, w1.y * sc, w1.z * sc, w1.w * sc};
    unsigned int word = 0u;
#pragma unroll
    for (int i = 0; i < 8; ++i) {
      float t = 0.f;
#pragma unroll
      for (int j = 0; j < 8; ++j)
        t = t + wsv[j] * Ms[j * 8 + i];   // contract(off): separate rn mul + rn add
      const int zi = (int)rintf(t);
      word |= (unsigned int)((zi + 2) & 3) << (2 * i);
    }
    z2[s] = (unsigned short)word;
  } else {
    const int s = (blockIdx.x - NQB) * 256 + tid;
    const int lane6 = s & 63;
    const int tile = s >> 6;
    const int m  = ((tile >> 7) << 4) + (lane6 & 15);
    const int kb = ((tile & 127) << 2) + (lane6 >> 4);
    const float4* xp = (const float4*)(x + ((size_t)m << 12) + ((size_t)kb << 3));
    const float4 a0 = xp[0], a1 = xp[1];
    float xv[8] = {a0.x, a0.y, a0.z, a0.w, a1.x, a1.y, a1.z, a1.w};
    unsigned int ph[4] = {0u, 0u, 0u, 0u}, pl[4] = {0u, 0u, 0u, 0u};
#pragma unroll
    for (int i = 0; i < 8; ++i) {
      float t = 0.f;
#pragma unroll
      for (int j = 0; j < 8; ++j) t = fmaf(xv[j], Ms[i * 8 + j], t);
      const unsigned short hb = f2bf(t);
      const float hf = __builtin_bit_cast(float, (unsigned int)hb << 16);
      const unsigned short lb = f2bf(t - hf);
      ph[i >> 1] |= ((unsigned int)hb) << ((i & 1) * 16);
      pl[i >> 1] |= ((unsigned int)lb) << ((i & 1) * 16);
    }
    *(uint4*)(hi + ((size_t)s << 3)) = make_uint4(ph[0], ph[1], ph[2], ph[3]);
    *(uint4*)(lo + ((size_t)s << 3)) = make_uint4(pl[0], pl[1], pl[2], pl[3]);
  }
}

// ---------- K2: tall-block split-K GEMM (wave = 32x64, -33% LDS traffic/MFMA) ----------
// grid 256 = (sk 4) x (nt 64), b&3 = sk -> each XCD serves one 1MB A-slice.
// 512 thr = 8 m-waves; wave w owns rows w*32..+32 x all 64 cols (mf=2, nf=4):
// 8 ds_read : 16 MFMA per step (vs R13's 6:8). LDS 36KB/buffer dbuf = 72KB,
// 2 blocks/CU. A: every wave async16's 4 contiguous-1KB chunks. B: waves 0-3
// stage 1 chunk each via z2 word (pipelined 1 ahead) + LUT zdec + ds_write
// (verified R13 path). 2-barrier __syncthreads schedule (proven). Per-acc
// MFMA k-order (ascending k32, hi-then-lo) = verified r3-r17.

__global__ __launch_bounds__(512, 2) void k_gemm(const unsigned short* __restrict__ xgh,
                                                 const unsigned short* __restrict__ xgl,
                                                 const unsigned short* __restrict__ z2,
                                                 float* __restrict__ part) {
  __shared__ uint4 smem4[2 * LDSBUF / 16];  // 72KB double buffer
  char* smem = (char*)smem4;

  const int tid = threadIdx.x;
  const int lane = tid & 63, wave = tid >> 6;
  const int b = blockIdx.x;
  const int sk = b & 3;
  const int nt = b >> 2;                     // 0..63
  const int k0t = sk * (KC / 32);            // base k-tile index
  const int lrow = lane & 15, lkg = lane >> 4;

  // A chunks: c 0..15 = A_hi row-tile c, 16..31 = A_lo row-tile c-16.
  // wave w stages chunks 4w..4w+3.
  const unsigned short* asrc[4];
  int aldo[4];
#pragma unroll
  for (int ci = 0; ci < 4; ++ci) {
    const int c = wave * 4 + ci;
    const unsigned short* P = (c < 16) ? xgh : xgl;
    const int rt = c & 15;
    asrc[ci] = P + (((size_t)(rt * 128 + k0t)) << 9) + lane * 8;
    aldo[ci] = c * 1024;
  }
  // B role (waves 0-3): B row-tile nt*4+wave -> chunk 32+wave
  const bool brole = (wave < 4);
  const unsigned short* zsrc = nullptr;
  int bofs = 0;
  if (brole) {
    zsrc = z2 + (((size_t)((nt * 4 + wave) * 128 + k0t)) << 6) + lane;
    bofs = (32 + wave) * 1024 + lane * 16;
  }

  f32x4 acc[2][4] = {};   // [mf][nf]

  // prologue: stage step 0 into buffer 0; preload zw for step 1
  unsigned int zw = 0;
#pragma unroll
  for (int ci = 0; ci < 4; ++ci) async16(asrc[ci], smem + aldo[ci]);
  if (brole) {
    zw = zsrc[0];
    *(uint4*)(smem + bofs) = zdec(zw);
    zw = zsrc[64];  // step 1 word
  }
  __syncthreads();

  for (int ks = 0; ks < KSTEPS; ++ks) {
    const int cur = (ks & 1) * LDSBUF;
    const int nxt = LDSBUF - cur;
    if (ks + 1 < KSTEPS) {
#pragma unroll
      for (int ci = 0; ci < 4; ++ci)
        async16(asrc[ci] + (size_t)(ks + 1) * 512, smem + nxt + aldo[ci]);
      if (brole) {
        *(uint4*)(smem + nxt + bofs) = zdec(zw);
        if (ks + 2 < KSTEPS) zw = zsrc[(size_t)(ks + 2) * 64];
      }
    }

    bf16x8 ah[2], al[2], bfr[4];
#pragma unroll
    for (int mf = 0; mf < 2; ++mf) {
      ah[mf] = *(const bf16x8*)(smem + cur + (wave * 2 + mf) * 1024 + lane * 16);
      al[mf] = *(const bf16x8*)(smem + cur + 16384 + (wave * 2 + mf) * 1024 + lane * 16);
    }
#pragma unroll
    for (int nf = 0; nf < 4; ++nf)
      bfr[nf] = *(const bf16x8*)(smem + cur + 32768 + nf * 1024 + lane * 16);

#pragma unroll
    for (int mf = 0; mf < 2; ++mf)
#pragma unroll
      for (int nf = 0; nf < 4; ++nf) {
        acc[mf][nf] = __builtin_amdgcn_mfma_f32_16x16x32_bf16(ah[mf], bfr[nf], acc[mf][nf], 0, 0, 0);
        acc[mf][nf] = __builtin_amdgcn_mfma_f32_16x16x32_bf16(al[mf], bfr[nf], acc[mf][nf], 0, 0, 0);
      }
    __syncthreads();  // drains vmcnt+lgkm: stage above targets NEXT buffer
  }

  // C/D layout (m89-verified): col = lane&15, row = (lane>>4)*4 + reg
  float* pb = part + (size_t)sk * (M_ * N_);
#pragma unroll
  for (int mf = 0; mf < 2; ++mf)
#pragma unroll
    for (int nf = 0; nf < 4; ++nf)
#pragma unroll
      for (int r = 0; r < 4; ++r) {
        const int m = wave * 32 + mf * 16 + lkg * 4 + r;
        const int n = nt * BN + nf * 16 + lrow;
        pb[(size_t)m * N_ + n] = acc[mf][nf][r];
      }
}

// ---------- K3: reduce 4 split-K partials + bias + LSQ epilogue (verified) ----------

__global__ __launch_bounds__(256) void k_epi(const float* __restrict__ part,
                                             const float* __restrict__ bias,
                                             const float* __restrict__ alpha,
                                             float* __restrict__ out) {
  const int i4 = blockIdx.x * 256 + threadIdx.x;  // over M_*N_/4
  const size_t off = (size_t)i4 * 4;
  const float4 p0 = *(const float4*)(part + off);
  const float4 p1 = *(const float4*)(part + (size_t)1 * M_ * N_ + off);
  const float4 p2 = *(const float4*)(part + (size_t)2 * M_ * N_ + off);
  const float4 p3 = *(const float4*)(part + (size_t)3 * M_ * N_ + off);
  const int n = (int)(off & (N_ - 1));
  const float4 bv = *(const float4*)(bias + n);
  const float a = fmaxf(alpha[0], 0.f) + 1e-8f;
  const float s = a / 127.0f;
  float4 o;
  o.x = lsq1(((p0.x + p1.x) + p2.x) + p3.x + bv.x, a, s);
  o.y = lsq1(((p0.y + p1.y) + p2.y) + p3.y + bv.y, a, s);
  o.z = lsq1(((p0.z + p1.z) + p2.z) + p3.z + bv.z, a, s);
  o.w = lsq1(((p0.w + p1.w) + p2.w) + p3.w + bv.w, a, s);
  *(float4*)(out + off) = o;
}

// ---------- launch ----------

extern "C" void kernel_launch(void* const* d_in, const int* in_sizes, int n_in,
                              void* d_out, int out_size, void* d_ws, size_t ws_size,
                              hipStream_t stream) {
  const float* x     = (const float*)d_in[0];
  const float* W     = (const float*)d_in[1];
  const float* bias  = (const float*)d_in[2];
  const float* theta = (const float*)d_in[3];
  const float* alpha = (const float*)d_in[4];
  const float* G     = (const float*)d_in[5];
  const float* Ginv  = (const float*)d_in[6];
  float* out = (float*)d_out;

  const int O = in_sizes[2];           // 4096
  const int kTheta = in_sizes[3] / O;  // 1

  // ws layout: xg_hi 2MB | xg_lo 2MB | z2 4MB | partials [4][M][N] 16MB
  char* ws = (char*)d_ws;
  unsigned short* xgh = (unsigned short*)ws;
  unsigned short* xgl = (unsigned short*)(ws + 2097152);
  unsigned short* z2  = (unsigned short*)(ws + 4194304);
  float* part = (float*)(ws + 8388608);
  if (ws_size < 25165824) return;  // guard: need 24MB scratch

  k_prep<<<NQB + NXB, 256, 0, stream>>>(W, theta, Ginv, x, G, z2, xgh, xgl, kTheta);
  k_gemm<<<SPLITK * (N_ / BN), 512, 0, stream>>>(xgh, xgl, z2, part);
  k_epi<<<(M_ * N_ / 4) / 256, 256, 0, stream>>>(part, bias, alpha, out);
}

// Round 19
// 51.423 us; speedup vs baseline: 1.3970x; 1.0202x over previous
//
#include <hip/hip_runtime.h>

typedef __attribute__((ext_vector_type(8))) __bf16 bf16x8;
typedef __attribute__((ext_vector_type(4))) float f32x4;

#define M_ 256
#define N_ 4096
#define K_ 4096
#define SPLITK 8
#define KC (K_ / SPLITK)   // 512
#define BM 256             // all of M per block
#define BN 128
#define BK 32
#define KSTEPS (KC / BK)   // 16
#define LDSBUF 40960       // per buffer: A_hi 16KB | A_lo 16KB | B 8KB

// Tiled operand layout: 1KB bf16 tile = 16 rows x 32 k; tile(rt,kt) index
// rt*128+kt; slot lane = (row&15)+16*((k>>3)&3), elem = k&7.
// xgh/xgl: 16B/slot bf16 (async16-staged). z2: 2B/slot = 8x2-bit indices,
// decoded in-GEMM (LUT) to the same bf16 bits — verified R13/R18.

// ---------- helpers ----------

__device__ __forceinline__ unsigned short f2bf(float f) {
  unsigned int u = __builtin_bit_cast(unsigned int, f);
  u += 0x7fffu + ((u >> 16) & 1u);
  return (unsigned short)(u >> 16);
}

__device__ __forceinline__ void async16(const void* g, void* l) {
  __builtin_amdgcn_global_load_lds(
      (const __attribute__((address_space(1))) unsigned int*)g,
      (__attribute__((address_space(3))) unsigned int*)l, 16, 0, 0);
}

__device__ __forceinline__ float lsq1(float y, float a, float s) {
  float yc = fminf(fmaxf(y, -a), a);
  return rintf(yc / s) * s;
}

// bf16 bit patterns for z_mod = idx-2: idx 0->-2, 1->-1, 2->0, 3->+1
#define ZLUT 0x3F800000BF80C000ull

// decode 8x2-bit word -> 16B (8 bf16), elem order ascending (verified R13)
__device__ __forceinline__ uint4 zdec(unsigned int w) {
  unsigned int d[4];
#pragma unroll
  for (int p = 0; p < 4; ++p) {
    const unsigned int lo = (unsigned int)((ZLUT >> (((w >> (4 * p)) & 3u) * 16)) & 0xFFFFull);
    const unsigned int hi = (unsigned int)((ZLUT >> (((w >> (4 * p + 2)) & 3u) * 16)) & 0xFFFFull);
    d[p] = lo | (hi << 16);
  }
  return make_uint4(d[0], d[1], d[2], d[3]);
}

// ---------- K1: fused producer (verified R13 — DO NOT TOUCH) ----------
// blocks [0, NQB): lattice-quantize W -> z2 (2-bit indices, tiled slot order).
//   z dot: f32 UNFUSED mul+add, sequential ascending, contract(off) — matches
//   XLA:CPU's fmul/fadd chain (contraction was the R1/R9/R10 0.701 bug).
// blocks [NQB, NQB+NXB): xg = x_blocks @ G^T -> bf16 hi/lo (tiled layout).

#define NQB ((N_ * K_ / 8) / 256)  // 8192
#define NXB ((M_ * K_ / 8) / 256)  // 512

__global__ __launch_bounds__(256) void k_prep(const float* __restrict__ W,
                                              const float* __restrict__ theta,
                                              const float* __restrict__ Ginv,
                                              const float* __restrict__ x,
                                              const float* __restrict__ G,
                                              unsigned short* __restrict__ z2,
                                              unsigned short* __restrict__ hi,
                                              unsigned short* __restrict__ lo,
                                              int kTheta) {
  __shared__ float Ms[64];
  const int tid = threadIdx.x;
  const bool isQ = blockIdx.x < NQB;
  if (tid < 64) Ms[tid] = isQ ? Ginv[tid] : G[tid];
  __syncthreads();

  if (isQ) {
#pragma clang fp contract(off)
    const int s = blockIdx.x * 256 + tid;       // output slot
    const int lane6 = s & 63;
    const int tile = s >> 6;
    const int o  = ((tile >> 7) << 4) + (lane6 & 15);   // W row
    const int kb = ((tile & 127) << 2) + (lane6 >> 4);  // 8-elt k-block
    const float4* wp = (const float4*)(W + ((size_t)o << 12) + ((size_t)kb << 3));
    const float4 w0 = wp[0], w1 = wp[1];
    float sc = 0.f;
    for (int t = 0; t < kTheta; ++t) sc += theta[o * kTheta + t];
    sc /= (float)kTheta;
    const float wsv[8] = {w0.x * sc, w0.y * sc, w0.z * sc, w0.w * sc,
                          w1.x * sc, w1.y * sc, w1.z * sc, w1.w * sc};
    unsigned int word = 0u;
#pragma unroll
    for (int i = 0; i < 8; ++i) {
      float t = 0.f;
#pragma unroll
      for (int j = 0; j < 8; ++j)
        t = t + wsv[j] * Ms[j * 8 + i];   // contract(off): separate rn mul + rn add
      const int zi = (int)rintf(t);
      word |= (unsigned int)((zi + 2) & 3) << (2 * i);
    }
    z2[s] = (unsigned short)word;
  } else {
    const int s = (blockIdx.x - NQB) * 256 + tid;
    const int lane6 = s & 63;
    const int tile = s >> 6;
    const int m  = ((tile >> 7) << 4) + (lane6 & 15);
    const int kb = ((tile & 127) << 2) + (lane6 >> 4);
    const float4* xp = (const float4*)(x + ((size_t)m << 12) + ((size_t)kb << 3));
    const float4 a0 = xp[0], a1 = xp[1];
    float xv[8] = {a0.x, a0.y, a0.z, a0.w, a1.x, a1.y, a1.z, a1.w};
    unsigned int ph[4] = {0u, 0u, 0u, 0u}, pl[4] = {0u, 0u, 0u, 0u};
#pragma unroll
    for (int i = 0; i < 8; ++i) {
      float t = 0.f;
#pragma unroll
      for (int j = 0; j < 8; ++j) t = fmaf(xv[j], Ms[i * 8 + j], t);
      const unsigned short hb = f2bf(t);
      const float hf = __builtin_bit_cast(float, (unsigned int)hb << 16);
      const unsigned short lb = f2bf(t - hf);
      ph[i >> 1] |= ((unsigned int)hb) << ((i & 1) * 16);
      pl[i >> 1] |= ((unsigned int)lb) << ((i & 1) * 16);
    }
    *(uint4*)(hi + ((size_t)s << 3)) = make_uint4(ph[0], ph[1], ph[2], ph[3]);
    *(uint4*)(lo + ((size_t)s << 3)) = make_uint4(pl[0], pl[1], pl[2], pl[3]);
  }
}

// ---------- K2: fat-wave split-K GEMM (wave = 64x64: 22.9 B/MFLOP, 2x better) ----------
// grid 256 = (sk 8) x (nt 32), b&7 = sk -> per-XCD ~1MB operand slice (L2).
// 512 thr = 8 waves (4m x 2n); wave owns 64 rows x 64 cols = 16 acc frags;
// per step: 12 ds_read_b128 : 32 MFMA (vs old 6:8 — halves LDS bytes/flop).
// LDS 40KB/buffer dbuf 80KB, 1 block/CU. KSTEPS=16 (fat steps amortize the
// per-step barrier-drain constant ~1.6k cyc, R11 measurement). Staging:
// every wave async16's 4 A-chunks + stages 1 B-chunk via z2 word (pipelined
// 1 ahead) + LUT zdec + ds_write (verified R13/R18 path). 2-barrier
// __syncthreads schedule (proven). Per-acc MFMA k-order (ascending k32,
// hi-then-lo) = verified r3-r18; only the split-K tree changes (4->8,
// epi reduces strictly sequentially — R11 showed this class is absorbed).

__global__ __launch_bounds__(512, 2) void k_gemm(const unsigned short* __restrict__ xgh,
                                                 const unsigned short* __restrict__ xgl,
                                                 const unsigned short* __restrict__ z2,
                                                 float* __restrict__ part) {
  __shared__ uint4 smem4[2 * LDSBUF / 16];  // 80KB double buffer
  char* smem = (char*)smem4;

  const int tid = threadIdx.x;
  const int lane = tid & 63, wave = tid >> 6;
  const int wr = wave >> 1, wc = wave & 1;   // wave grid 4m x 2n
  const int b = blockIdx.x;
  const int sk = b & 7;
  const int nt = b >> 3;                     // 0..31
  const int k0t = sk * (KC / 32);            // base k-tile index (sk*16)
  const int lrow = lane & 15, lkg = lane >> 4;

  // A chunks: c 0..15 = A_hi row-tile c, 16..31 = A_lo row-tile c-16.
  // wave w stages chunks 4w..4w+3 (w<4: A_hi; w>=4: A_lo).
  const unsigned short* asrc[4];
  int aldo[4];
#pragma unroll
  for (int ci = 0; ci < 4; ++ci) {
    const int c = wave * 4 + ci;
    const unsigned short* P = (c < 16) ? xgh : xgl;
    const int rt = c & 15;
    asrc[ci] = P + (((size_t)(rt * 128 + k0t)) << 9) + lane * 8;
    aldo[ci] = c * 1024;
  }
  // B: every wave stages col-tile `wave` -> chunk 32+wave
  const unsigned short* zsrc = z2 + (((size_t)((nt * 8 + wave) * 128 + k0t)) << 6) + lane;
  const int bofs = (32 + wave) * 1024 + lane * 16;

  f32x4 acc[4][4] = {};   // [mf][nf]

  // prologue: stage step 0 into buffer 0; preload zw for step 1
#pragma unroll
  for (int ci = 0; ci < 4; ++ci) async16(asrc[ci], smem + aldo[ci]);
  unsigned int zw = zsrc[0];
  *(uint4*)(smem + bofs) = zdec(zw);
  zw = zsrc[64];  // step 1 word
  __syncthreads();

  for (int ks = 0; ks < KSTEPS; ++ks) {
    const int cur = (ks & 1) * LDSBUF;
    const int nxt = LDSBUF - cur;
    if (ks + 1 < KSTEPS) {
#pragma unroll
      for (int ci = 0; ci < 4; ++ci)
        async16(asrc[ci] + (size_t)(ks + 1) * 512, smem + nxt + aldo[ci]);
      *(uint4*)(smem + nxt + bofs) = zdec(zw);
      if (ks + 2 < KSTEPS) zw = zsrc[(size_t)(ks + 2) * 64];
    }

    bf16x8 ah[4], al[4], bfr[4];
#pragma unroll
    for (int mf = 0; mf < 4; ++mf) {
      ah[mf] = *(const bf16x8*)(smem + cur + (wr * 4 + mf) * 1024 + lane * 16);
      al[mf] = *(const bf16x8*)(smem + cur + 16384 + (wr * 4 + mf) * 1024 + lane * 16);
    }
#pragma unroll
    for (int nf = 0; nf < 4; ++nf)
      bfr[nf] = *(const bf16x8*)(smem + cur + 32768 + (wc * 4 + nf) * 1024 + lane * 16);

#pragma unroll
    for (int mf = 0; mf < 4; ++mf)
#pragma unroll
      for (int nf = 0; nf < 4; ++nf) {
        acc[mf][nf] = __builtin_amdgcn_mfma_f32_16x16x32_bf16(ah[mf], bfr[nf], acc[mf][nf], 0, 0, 0);
        acc[mf][nf] = __builtin_amdgcn_mfma_f32_16x16x32_bf16(al[mf], bfr[nf], acc[mf][nf], 0, 0, 0);
      }
    __syncthreads();  // drains vmcnt+lgkm: stage above targets NEXT buffer
  }

  // C/D layout (m89-verified): col = lane&15, row = (lane>>4)*4 + reg
  float* pb = part + (size_t)sk * (M_ * N_);
#pragma unroll
  for (int mf = 0; mf < 4; ++mf)
#pragma unroll
    for (int nf = 0; nf < 4; ++nf)
#pragma unroll
      for (int r = 0; r < 4; ++r) {
        const int m = wr * 64 + mf * 16 + lkg * 4 + r;
        const int n = nt * BN + wc * 64 + nf * 16 + lrow;
        pb[(size_t)m * N_ + n] = acc[mf][nf][r];
      }
}

// ---------- K3: reduce 8 split-K partials + bias + LSQ epilogue ----------
// strictly sequential sum p0..p7 + bias (extends the verified k_epi order)

__global__ __launch_bounds__(256) void k_epi(const float* __restrict__ part,
                                             const float* __restrict__ bias,
                                             const float* __restrict__ alpha,
                                             float* __restrict__ out) {
  const int i4 = blockIdx.x * 256 + threadIdx.x;  // over M_*N_/4
  const size_t off = (size_t)i4 * 4;
  float4 acc = *(const float4*)(part + off);
#pragma unroll
  for (int p = 1; p < SPLITK; ++p) {
    const float4 q = *(const float4*)(part + (size_t)p * M_ * N_ + off);
    acc.x += q.x; acc.y += q.y; acc.z += q.z; acc.w += q.w;
  }
  const int n = (int)(off & (N_ - 1));
  const float4 bv = *(const float4*)(bias + n);
  const float a = fmaxf(alpha[0], 0.f) + 1e-8f;
  const float s = a / 127.0f;
  float4 o;
  o.x = lsq1(acc.x + bv.x, a, s);
  o.y = lsq1(acc.y + bv.y, a, s);
  o.z = lsq1(acc.z + bv.z, a, s);
  o.w = lsq1(acc.w + bv.w, a, s);
  *(float4*)(out + off) = o;
}

// ---------- launch ----------

extern "C" void kernel_launch(void* const* d_in, const int* in_sizes, int n_in,
                              void* d_out, int out_size, void* d_ws, size_t ws_size,
                              hipStream_t stream) {
  const float* x     = (const float*)d_in[0];
  const float* W     = (const float*)d_in[1];
  const float* bias  = (const float*)d_in[2];
  const float* theta = (const float*)d_in[3];
  const float* alpha = (const float*)d_in[4];
  const float* G     = (const float*)d_in[5];
  const float* Ginv  = (const float*)d_in[6];
  float* out = (float*)d_out;

  const int O = in_sizes[2];           // 4096
  const int kTheta = in_sizes[3] / O;  // 1

  // ws layout: xg_hi 2MB | xg_lo 2MB | z2 4MB | partials [8][M][N] 32MB
  char* ws = (char*)d_ws;
  unsigned short* xgh = (unsigned short*)ws;
  unsigned short* xgl = (unsigned short*)(ws + 2097152);
  unsigned short* z2  = (unsigned short*)(ws + 4194304);
  float* part = (float*)(ws + 8388608);
  if (ws_size < 41943040) return;  // guard: need 40MB scratch

  k_prep<<<NQB + NXB, 256, 0, stream>>>(W, theta, Ginv, x, G, z2, xgh, xgl, kTheta);
  k_gemm<<<SPLITK * (N_ / BN), 512, 0, stream>>>(xgh, xgl, z2, part);
  k_epi<<<(M_ * N_ / 4) / 256, 256, 0, stream>>>(part, bias, alpha, out);
}